// Round 5
// baseline (191.614 us; speedup 1.0000x reference)
//
#include <hip/hip_runtime.h>

#define DIM     1024
#define BATCH   512
#define OUTD    5377
#define NHEADS  10
#define NLAYERS 5
#define LDK     72   // padded bf16 leading dim (144 B -> benign bank aliasing)

typedef __attribute__((ext_vector_type(4))) float f32x4;
typedef __attribute__((ext_vector_type(8))) short bf16x8;

__device__ __forceinline__ unsigned short f2bf(float f) {
    unsigned u = __builtin_bit_cast(unsigned, f);
    u = (u + 0x7FFFu + ((u >> 16) & 1u)) >> 16;
    return (unsigned short)u;
}
__device__ __forceinline__ float bf2f(unsigned short h) {
    unsigned u = ((unsigned)h) << 16;
    return __builtin_bit_cast(float, u);
}
__device__ __forceinline__ unsigned pk2(float a, float b) {
    return (unsigned)f2bf(a) | ((unsigned)f2bf(b) << 16);
}

// ---------------- grouping: bucket batches by rule_len ----------------
__global__ void group_kernel(const int* __restrict__ rule_len,
                             int* __restrict__ bidx,
                             int* __restrict__ gstart,
                             int* __restrict__ gcount) {
    __shared__ int s_count[NHEADS];
    __shared__ int s_fill[NHEADS];
    int t = threadIdx.x;
    if (t < NHEADS) s_count[t] = 0;
    __syncthreads();
    int h = rule_len[t];
    atomicAdd(&s_count[h], 1);
    __syncthreads();
    if (t == 0) {
        int acc = 0;
        for (int i = 0; i < NHEADS; ++i) {
            gstart[i] = acc;
            gcount[i] = s_count[i];
            s_fill[i] = acc;
            acc += s_count[i];
        }
    }
    __syncthreads();
    int pos = atomicAdd(&s_fill[h], 1);
    bidx[pos] = t;
}

// ---------------- latent f32 -> bf16 ----------------
__global__ void convert_latent(const float* __restrict__ in,
                               unsigned short* __restrict__ out) {
    int i = blockIdx.x * blockDim.x + threadIdx.x;   // one float4 per thread
    float4 v = ((const float4*)in)[i];
    ushort4 o;
    o.x = f2bf(v.x); o.y = f2bf(v.y); o.z = f2bf(v.z); o.w = f2bf(v.w);
    ((ushort4*)out)[i] = o;
}

// ---------------- MLP layer: C = A @ W^T + bias  (MFMA, W hi/lo, pipelined) --
__global__ __launch_bounds__(256) void mlp_mfma(
    const unsigned short* __restrict__ A,
    const float* __restrict__ W,
    const float* __restrict__ bias,
    unsigned short* __restrict__ C)
{
    __shared__ __align__(16) unsigned short As[2][32][LDK];
    __shared__ __align__(16) unsigned short Whi[2][32][LDK];
    __shared__ __align__(16) unsigned short Wlo[2][32][LDK];

    const int tid = threadIdx.x;
    const int n0 = blockIdx.x * 32;
    const int m0 = blockIdx.y * 32;
    const int lane = tid & 63;
    const int wid = tid >> 6;
    const int wm = (wid >> 1) * 16;
    const int wn = (wid & 1) * 16;

    f32x4 acc = {0.f, 0.f, 0.f, 0.f};

    const int ar = tid >> 3;          // 0..31
    const int ac = (tid & 7) * 8;     // 0..56 bf16 units
    const int wr = tid >> 4;          // 0..15
    const int wc = (tid & 15) * 4;    // 0..60 f32 units

    const unsigned short* Ap = A + (size_t)(m0 + ar) * DIM + ac;
    const float* Wp0 = W + (size_t)(n0 + wr) * DIM + wc;
    const float* Wp1 = W + (size_t)(n0 + wr + 16) * DIM + wc;

    uint4  ra  = *(const uint4*)(Ap);
    float4 rw0 = *(const float4*)(Wp0);
    float4 rw1 = *(const float4*)(Wp1);

    for (int t = 0; t < DIM / 64; ++t) {
        const int cur = t & 1;
        *(uint4*)&As[cur][ar][ac] = ra;
        {
            ushort4 hi, lo;
            hi.x = f2bf(rw0.x); lo.x = f2bf(rw0.x - bf2f(hi.x));
            hi.y = f2bf(rw0.y); lo.y = f2bf(rw0.y - bf2f(hi.y));
            hi.z = f2bf(rw0.z); lo.z = f2bf(rw0.z - bf2f(hi.z));
            hi.w = f2bf(rw0.w); lo.w = f2bf(rw0.w - bf2f(hi.w));
            *(ushort4*)&Whi[cur][wr][wc] = hi;
            *(ushort4*)&Wlo[cur][wr][wc] = lo;
            hi.x = f2bf(rw1.x); lo.x = f2bf(rw1.x - bf2f(hi.x));
            hi.y = f2bf(rw1.y); lo.y = f2bf(rw1.y - bf2f(hi.y));
            hi.z = f2bf(rw1.z); lo.z = f2bf(rw1.z - bf2f(hi.z));
            hi.w = f2bf(rw1.w); lo.w = f2bf(rw1.w - bf2f(hi.w));
            *(ushort4*)&Whi[cur][wr + 16][wc] = hi;
            *(ushort4*)&Wlo[cur][wr + 16][wc] = lo;
        }
        __syncthreads();
        if (t < DIM / 64 - 1) {
            const int k0 = (t + 1) * 64;
            ra  = *(const uint4*)(Ap + k0);
            rw0 = *(const float4*)(Wp0 + k0);
            rw1 = *(const float4*)(Wp1 + k0);
        }
        #pragma unroll
        for (int kk = 0; kk < 2; ++kk) {
            const int ko = kk * 32 + (lane >> 4) * 8;
            bf16x8 a  = *(const bf16x8*)&As[cur][wm + (lane & 15)][ko];
            bf16x8 bh = *(const bf16x8*)&Whi[cur][wn + (lane & 15)][ko];
            bf16x8 bl = *(const bf16x8*)&Wlo[cur][wn + (lane & 15)][ko];
            acc = __builtin_amdgcn_mfma_f32_16x16x32_bf16(a, bh, acc, 0, 0, 0);
            acc = __builtin_amdgcn_mfma_f32_16x16x32_bf16(a, bl, acc, 0, 0, 0);
        }
    }

    const int cn = n0 + wn + (lane & 15);
    const float bn = bias[cn];
    const int rbase = m0 + wm + (lane >> 4) * 4;
    #pragma unroll
    for (int j = 0; j < 4; ++j) {
        C[(size_t)(rbase + j) * DIM + cn] = f2bf(acc[j] + bn);
    }
}

// ------- head: LDS-free, barrier-free direct-MFMA stream ---------------------
// Per wave: output tile 64m x 16n. Each lane loads its MFMA fragments straight
// from global: A-frag = 16 contiguous B of H (bf16x8), B-frag = 32 contiguous B
// of W (f32x8 -> pk to bf16x8). No staging, no barriers; latency hidden by
// 13 waves/CU TLP + unrolled-load ILP. W_heads read exactly once (m covers cnt).
__global__ __launch_bounds__(256, 4) void head_stream(
    const unsigned short* __restrict__ H,   // BATCH x DIM bf16
    const float* __restrict__ Wh,           // NHEADS x OUTD x DIM f32
    const float* __restrict__ bh,           // NHEADS x OUTD f32
    const int* __restrict__ bidx,
    const int* __restrict__ gstart,
    const int* __restrict__ gcount,
    float* __restrict__ out)                // BATCH x OUTD f32
{
    const int head = blockIdx.z;
    const int cnt  = gcount[head];
    const int m0   = blockIdx.y * 64;
    if (m0 >= cnt) return;
    const int start = gstart[head];

    const int lane = threadIdx.x & 63;
    const int wv   = threadIdx.x >> 6;
    const int n0   = (blockIdx.x * 4 + wv) * 16;
    const int col  = lane & 15;
    const int koff = (lane >> 4) * 8;       // k element offset within a k-step

    int wrow = n0 + col; if (wrow > OUTD - 1) wrow = OUTD - 1;
    const float* wp = Wh + (size_t)head * OUTD * DIM + (size_t)wrow * DIM + koff;

    const unsigned short* ap[4];
    #pragma unroll
    for (int mf = 0; mf < 4; ++mf) {
        int m = m0 + mf * 16 + col;
        int idx = (m < cnt) ? m : (cnt - 1);
        int b = bidx[start + idx];
        ap[mf] = H + (size_t)b * DIM + koff;
    }

    f32x4 acc[4] = {};

    #pragma unroll 4
    for (int eo = 0; eo < DIM; eo += 32) {
        float4 w0 = *(const float4*)(wp + eo);
        float4 w1 = *(const float4*)(wp + eo + 4);
        bf16x8 a0 = *(const bf16x8*)(ap[0] + eo);
        bf16x8 a1 = *(const bf16x8*)(ap[1] + eo);
        bf16x8 a2 = *(const bf16x8*)(ap[2] + eo);
        bf16x8 a3 = *(const bf16x8*)(ap[3] + eo);
        uint4 wk;
        wk.x = pk2(w0.x, w0.y);
        wk.y = pk2(w0.z, w0.w);
        wk.z = pk2(w1.x, w1.y);
        wk.w = pk2(w1.z, w1.w);
        bf16x8 wb = __builtin_bit_cast(bf16x8, wk);
        acc[0] = __builtin_amdgcn_mfma_f32_16x16x32_bf16(a0, wb, acc[0], 0, 0, 0);
        acc[1] = __builtin_amdgcn_mfma_f32_16x16x32_bf16(a1, wb, acc[1], 0, 0, 0);
        acc[2] = __builtin_amdgcn_mfma_f32_16x16x32_bf16(a2, wb, acc[2], 0, 0, 0);
        acc[3] = __builtin_amdgcn_mfma_f32_16x16x32_bf16(a3, wb, acc[3], 0, 0, 0);
    }

    const int n = n0 + col;
    if (n < OUTD) {
        const float bn = bh[(size_t)head * OUTD + n];
        #pragma unroll
        for (int mf = 0; mf < 4; ++mf) {
            #pragma unroll
            for (int j = 0; j < 4; ++j) {
                int m = m0 + mf * 16 + (lane >> 4) * 4 + j;
                if (m < cnt) {
                    int b = bidx[start + m];
                    out[(size_t)b * OUTD + n] = acc[mf][j] + bn;
                }
            }
        }
    }
}

extern "C" void kernel_launch(void* const* d_in, const int* in_sizes, int n_in,
                              void* d_out, int out_size, void* d_ws, size_t ws_size,
                              hipStream_t stream) {
    const float* latent   = (const float*)d_in[0];
    const float* W_mlp    = (const float*)d_in[1];
    const float* b_mlp    = (const float*)d_in[2];
    const float* W_heads  = (const float*)d_in[3];
    const float* b_heads  = (const float*)d_in[4];
    const int*   rule_len = (const int*)d_in[5];
    float* out = (float*)d_out;

    unsigned short* h0 = (unsigned short*)d_ws;
    unsigned short* h1 = h0 + (size_t)BATCH * DIM;
    int* bidx   = (int*)(h1 + (size_t)BATCH * DIM);
    int* gstart = bidx + BATCH;
    int* gcount = gstart + 16;

    group_kernel<<<1, BATCH, 0, stream>>>(rule_len, bidx, gstart, gcount);
    convert_latent<<<(BATCH * DIM / 4) / 256, 256, 0, stream>>>(latent, h0);

    dim3 mgrid(DIM / 32, BATCH / 32);
    const unsigned short* src = h0;
    unsigned short* dst = h1;
    for (int l = 0; l < NLAYERS; ++l) {
        mlp_mfma<<<mgrid, 256, 0, stream>>>(src,
                                            W_mlp + (size_t)l * DIM * DIM,
                                            b_mlp + (size_t)l * DIM,
                                            dst);
        unsigned short* t = (unsigned short*)src;
        src = dst;
        dst = t;
    }

    // 64-wide n per block (4 waves x 16), m covered 64/block, z = head
    dim3 hgrid((OUTD + 63) / 64, BATCH / 64, NHEADS);
    head_stream<<<hgrid, 256, 0, stream>>>(src, W_heads, b_heads,
                                           bidx, gstart, gcount, out);
}

// Round 6
// 132.535 us; speedup vs baseline: 1.4458x; 1.4458x over previous
//
#include <hip/hip_runtime.h>

#define DIM     1024
#define BATCH   512
#define OUTD    5377
#define NHEADS  10
#define NLAYERS 5
#define LDK     72   // padded bf16 leading dim for MLP tiles
#define KS      64   // head k-step

typedef __attribute__((ext_vector_type(4))) float f32x4;
typedef __attribute__((ext_vector_type(8))) short bf16x8;

__device__ __forceinline__ unsigned short f2bf(float f) {
    unsigned u = __builtin_bit_cast(unsigned, f);
    u = (u + 0x7FFFu + ((u >> 16) & 1u)) >> 16;
    return (unsigned short)u;
}
__device__ __forceinline__ float bf2f(unsigned short h) {
    unsigned u = ((unsigned)h) << 16;
    return __builtin_bit_cast(float, u);
}
__device__ __forceinline__ unsigned pk2(float a, float b) {
    return (unsigned)f2bf(a) | ((unsigned)f2bf(b) << 16);
}
__device__ __forceinline__ void gload16(const void* g, void* l) {
    __builtin_amdgcn_global_load_lds(
        (const __attribute__((address_space(1))) unsigned int*)g,
        (__attribute__((address_space(3))) unsigned int*)l,
        16, 0, 0);
}

// ---------------- grouping: bucket batches by rule_len ----------------
__global__ void group_kernel(const int* __restrict__ rule_len,
                             int* __restrict__ bidx,
                             int* __restrict__ gstart,
                             int* __restrict__ gcount) {
    __shared__ int s_count[NHEADS];
    __shared__ int s_fill[NHEADS];
    int t = threadIdx.x;
    if (t < NHEADS) s_count[t] = 0;
    __syncthreads();
    int h = rule_len[t];
    atomicAdd(&s_count[h], 1);
    __syncthreads();
    if (t == 0) {
        int acc = 0;
        for (int i = 0; i < NHEADS; ++i) {
            gstart[i] = acc;
            gcount[i] = s_count[i];
            s_fill[i] = acc;
            acc += s_count[i];
        }
    }
    __syncthreads();
    int pos = atomicAdd(&s_fill[h], 1);
    bidx[pos] = t;
}

// ---------------- latent f32 -> bf16 ----------------
__global__ void convert_latent(const float* __restrict__ in,
                               unsigned short* __restrict__ out) {
    int i = blockIdx.x * blockDim.x + threadIdx.x;   // one float4 per thread
    float4 v = ((const float4*)in)[i];
    ushort4 o;
    o.x = f2bf(v.x); o.y = f2bf(v.y); o.z = f2bf(v.z); o.w = f2bf(v.w);
    ((ushort4*)out)[i] = o;
}

// ---------------- MLP layer: C = A @ W^T + bias  (MFMA, W hi/lo, pipelined) --
__global__ __launch_bounds__(256) void mlp_mfma(
    const unsigned short* __restrict__ A,
    const float* __restrict__ W,
    const float* __restrict__ bias,
    unsigned short* __restrict__ C)
{
    __shared__ __align__(16) unsigned short As[2][32][LDK];
    __shared__ __align__(16) unsigned short Whi[2][32][LDK];
    __shared__ __align__(16) unsigned short Wlo[2][32][LDK];

    const int tid = threadIdx.x;
    const int n0 = blockIdx.x * 32;
    const int m0 = blockIdx.y * 32;
    const int lane = tid & 63;
    const int wid = tid >> 6;
    const int wm = (wid >> 1) * 16;
    const int wn = (wid & 1) * 16;

    f32x4 acc = {0.f, 0.f, 0.f, 0.f};

    const int ar = tid >> 3;          // 0..31
    const int ac = (tid & 7) * 8;     // 0..56 bf16 units
    const int wr = tid >> 4;          // 0..15
    const int wc = (tid & 15) * 4;    // 0..60 f32 units

    const unsigned short* Ap = A + (size_t)(m0 + ar) * DIM + ac;
    const float* Wp0 = W + (size_t)(n0 + wr) * DIM + wc;
    const float* Wp1 = W + (size_t)(n0 + wr + 16) * DIM + wc;

    uint4  ra  = *(const uint4*)(Ap);
    float4 rw0 = *(const float4*)(Wp0);
    float4 rw1 = *(const float4*)(Wp1);

    for (int t = 0; t < DIM / 64; ++t) {
        const int cur = t & 1;
        *(uint4*)&As[cur][ar][ac] = ra;
        {
            ushort4 hi, lo;
            hi.x = f2bf(rw0.x); lo.x = f2bf(rw0.x - bf2f(hi.x));
            hi.y = f2bf(rw0.y); lo.y = f2bf(rw0.y - bf2f(hi.y));
            hi.z = f2bf(rw0.z); lo.z = f2bf(rw0.z - bf2f(hi.z));
            hi.w = f2bf(rw0.w); lo.w = f2bf(rw0.w - bf2f(hi.w));
            *(ushort4*)&Whi[cur][wr][wc] = hi;
            *(ushort4*)&Wlo[cur][wr][wc] = lo;
            hi.x = f2bf(rw1.x); lo.x = f2bf(rw1.x - bf2f(hi.x));
            hi.y = f2bf(rw1.y); lo.y = f2bf(rw1.y - bf2f(hi.y));
            hi.z = f2bf(rw1.z); lo.z = f2bf(rw1.z - bf2f(hi.z));
            hi.w = f2bf(rw1.w); lo.w = f2bf(rw1.w - bf2f(hi.w));
            *(ushort4*)&Whi[cur][wr + 16][wc] = hi;
            *(ushort4*)&Wlo[cur][wr + 16][wc] = lo;
        }
        __syncthreads();
        if (t < DIM / 64 - 1) {
            const int k0 = (t + 1) * 64;
            ra  = *(const uint4*)(Ap + k0);
            rw0 = *(const float4*)(Wp0 + k0);
            rw1 = *(const float4*)(Wp1 + k0);
        }
        #pragma unroll
        for (int kk = 0; kk < 2; ++kk) {
            const int ko = kk * 32 + (lane >> 4) * 8;
            bf16x8 a  = *(const bf16x8*)&As[cur][wm + (lane & 15)][ko];
            bf16x8 bh = *(const bf16x8*)&Whi[cur][wn + (lane & 15)][ko];
            bf16x8 bl = *(const bf16x8*)&Wlo[cur][wn + (lane & 15)][ko];
            acc = __builtin_amdgcn_mfma_f32_16x16x32_bf16(a, bh, acc, 0, 0, 0);
            acc = __builtin_amdgcn_mfma_f32_16x16x32_bf16(a, bl, acc, 0, 0, 0);
        }
    }

    const int cn = n0 + wn + (lane & 15);
    const float bn = bias[cn];
    const int rbase = m0 + wm + (lane >> 4) * 4;
    #pragma unroll
    for (int j = 0; j < 4; ++j) {
        C[(size_t)(rbase + j) * DIM + cn] = f2bf(acc[j] + bn);
    }
}

// ------- head: global_load_lds streaming GEMM, counted-vmcnt pipeline --------
// 64m x 64n tile, BK=64. W staged as f32 via global_load_lds (swizzled source,
// linear LDS dest, swizzled read - rule both-sides-or-neither). 2-step-deep
// prefetch kept in flight across raw barriers via vmcnt(6).
__global__ __launch_bounds__(256, 3) void head_glds(
    const unsigned short* __restrict__ H,   // BATCH x DIM bf16
    const float* __restrict__ Wh,           // NHEADS x OUTD x DIM f32
    const float* __restrict__ bh,           // NHEADS x OUTD f32
    const int* __restrict__ bidx,
    const int* __restrict__ gstart,
    const int* __restrict__ gcount,
    float* __restrict__ out)                // BATCH x OUTD f32
{
    const int head = blockIdx.z;
    const int cnt  = gcount[head];
    const int m0   = blockIdx.y * 64;
    if (m0 >= cnt) return;
    const int n0   = blockIdx.x * 64;
    const int start = gstart[head];

    __shared__ __align__(16) float          Wb[2][64][KS];   // 32 KB
    __shared__ __align__(16) unsigned short Ab[2][64][KS];   // 16 KB
    __shared__ int s_b[64];

    const int tid  = threadIdx.x;
    const int lane = tid & 63;
    const int wv   = tid >> 6;

    if (tid < 64) {
        int mi = m0 + tid;
        s_b[tid] = bidx[start + ((mi < cnt) ? mi : (cnt - 1))];
    }
    __syncthreads();

    // ---- staging geometry (linear LDS dest, inverse-swizzled global src) ----
    // A: 512 slots x 16B. slot = p*256+tid; row = slot>>3; bx = (slot&7)*16.
    const int rA  = tid >> 3;            // p=0 row; p=1 row = rA+32 (same &7)
    const int axs = (tid & 7) * 16;
    const char* gA0 = (const char*)(H + (size_t)s_b[rA] * DIM)
                      + (axs ^ ((rA & 7) << 4));
    const char* gA1 = (const char*)(H + (size_t)s_b[rA + 32] * DIM)
                      + (axs ^ ((rA & 7) << 4));
    // W: 1024 slots x 16B. slot = p*256+tid; row = p*16 + (tid>>4); bx=(tid&15)*16.
    const int wxs = (tid & 15) * 16;
    const float* WhL = Wh + (size_t)head * OUTD * DIM;
    const char* gW[4];
    #pragma unroll
    for (int p = 0; p < 4; ++p) {
        int r = p * 16 + (tid >> 4);
        int grow = n0 + r; if (grow > OUTD - 1) grow = OUTD - 1;
        int sw = ((r & 3) << 5) | ((r & 4) << 2);
        gW[p] = (const char*)(WhL + (size_t)grow * DIM) + (wxs ^ sw);
    }

    char* ldsA = (char*)&Ab[0][0][0];
    char* ldsW = (char*)&Wb[0][0][0];

    auto stage = [&](int buf, int k0) {
        gload16(gA0 + (size_t)k0 * 2, ldsA + buf * 8192 + tid * 16);
        gload16(gA1 + (size_t)k0 * 2, ldsA + buf * 8192 + 4096 + tid * 16);
        #pragma unroll
        for (int p = 0; p < 4; ++p)
            gload16(gW[p] + (size_t)k0 * 4,
                    ldsW + buf * 16384 + p * 4096 + tid * 16);
    };

    const int col = lane & 15;
    const int hk  = lane >> 4;                       // 0..3
    const int nr  = wv * 16 + col;                   // this lane's W row
    const int swn = ((col & 3) << 5) | ((col & 4) << 2);
    const int swa = (col & 7) << 4;

    f32x4 acc[4] = {};

    auto compute = [&](int buf) {
        const char* wrow  = ldsW + buf * 16384 + nr * 256;
        const char* abase = ldsA + buf * 8192;
        #pragma unroll
        for (int ksub = 0; ksub < 2; ++ksub) {
            int wb_ = ksub * 128 + hk * 32;
            f32x4 w0 = *(const f32x4*)(wrow + ( wb_        ^ swn));
            f32x4 w1 = *(const f32x4*)(wrow + ((wb_ + 16)  ^ swn));
            uint4 wk;
            wk.x = pk2(w0.x, w0.y); wk.y = pk2(w0.z, w0.w);
            wk.z = pk2(w1.x, w1.y); wk.w = pk2(w1.z, w1.w);
            bf16x8 wfrag = __builtin_bit_cast(bf16x8, wk);
            int ab_ = (ksub * 64 + hk * 16) ^ swa;
            #pragma unroll
            for (int mf = 0; mf < 4; ++mf) {
                bf16x8 a = *(const bf16x8*)(abase + (mf * 16 + col) * 128 + ab_);
                acc[mf] = __builtin_amdgcn_mfma_f32_16x16x32_bf16(a, wfrag, acc[mf], 0, 0, 0);
            }
        }
    };

    stage(0, 0);
    stage(1, KS);

    for (int t = 0; t < DIM / KS - 2; ++t) {        // t = 0..13
        asm volatile("s_waitcnt vmcnt(6)" ::: "memory");   // own stage(t) done
        __builtin_amdgcn_sched_barrier(0);
        __builtin_amdgcn_s_barrier();                      // all waves' stage(t) done
        __builtin_amdgcn_sched_barrier(0);
        compute(t & 1);
        __builtin_amdgcn_sched_barrier(0);
        asm volatile("s_waitcnt lgkmcnt(0)" ::: "memory"); // reads retired
        __builtin_amdgcn_s_barrier();                      // buf free for overwrite
        __builtin_amdgcn_sched_barrier(0);
        stage(t & 1, (t + 2) * KS);                        // overlaps next step
    }
    // t = 14: compute buf0, nothing left to stage
    asm volatile("s_waitcnt vmcnt(6)" ::: "memory");
    __builtin_amdgcn_sched_barrier(0);
    __builtin_amdgcn_s_barrier();
    __builtin_amdgcn_sched_barrier(0);
    compute(0);
    // t = 15: drain and compute buf1
    asm volatile("s_waitcnt vmcnt(0)" ::: "memory");
    __builtin_amdgcn_sched_barrier(0);
    __builtin_amdgcn_s_barrier();
    __builtin_amdgcn_sched_barrier(0);
    compute(1);

    const int n = n0 + nr;
    if (n < OUTD) {
        const float bn = bh[(size_t)head * OUTD + n];
        #pragma unroll
        for (int mf = 0; mf < 4; ++mf) {
            #pragma unroll
            for (int j = 0; j < 4; ++j) {
                int row = mf * 16 + hk * 4 + j;
                if (m0 + row < cnt) {
                    out[(size_t)s_b[row] * OUTD + n] = acc[mf][j] + bn;
                }
            }
        }
    }
}

extern "C" void kernel_launch(void* const* d_in, const int* in_sizes, int n_in,
                              void* d_out, int out_size, void* d_ws, size_t ws_size,
                              hipStream_t stream) {
    const float* latent   = (const float*)d_in[0];
    const float* W_mlp    = (const float*)d_in[1];
    const float* b_mlp    = (const float*)d_in[2];
    const float* W_heads  = (const float*)d_in[3];
    const float* b_heads  = (const float*)d_in[4];
    const int*   rule_len = (const int*)d_in[5];
    float* out = (float*)d_out;

    unsigned short* h0 = (unsigned short*)d_ws;
    unsigned short* h1 = h0 + (size_t)BATCH * DIM;
    int* bidx   = (int*)(h1 + (size_t)BATCH * DIM);
    int* gstart = bidx + BATCH;
    int* gcount = gstart + 16;

    group_kernel<<<1, BATCH, 0, stream>>>(rule_len, bidx, gstart, gcount);
    convert_latent<<<(BATCH * DIM / 4) / 256, 256, 0, stream>>>(latent, h0);

    dim3 mgrid(DIM / 32, BATCH / 32);
    const unsigned short* src = h0;
    unsigned short* dst = h1;
    for (int l = 0; l < NLAYERS; ++l) {
        mlp_mfma<<<mgrid, 256, 0, stream>>>(src,
                                            W_mlp + (size_t)l * DIM * DIM,
                                            b_mlp + (size_t)l * DIM,
                                            dst);
        unsigned short* t = (unsigned short*)src;
        src = dst;
        dst = t;
    }

    dim3 hgrid((OUTD + 63) / 64, BATCH / 64, NHEADS);
    head_glds<<<hgrid, 256, 0, stream>>>(src, W_heads, b_heads,
                                         bidx, gstart, gcount, out);
}